// Round 7
// baseline (146.235 us; speedup 1.0000x reference)
//
#include <hip/hip_runtime.h>

typedef float f4 __attribute__((ext_vector_type(4)));

#define BB   16
#define NN   512
#define DIN  256
#define COUT 32
#define CCS  48
#define HH   256
#define WWG  256
#define HW   (HH * WWG)          // 65536 = 1<<16
#define CTOT (CCS + COUT)        // 80

#define NGEMM 1024               // BB*NN/8

// ---------------------------------------------------------------------------
// Node 1: proj GEMM (blocks 0..1023, LDS-free) + winner map (block 1024).
// Winner block: write -1 to the touched cells, __syncthreads, then
// atomicMax(flat entity index) — max flat index == last-write-wins.
// Replay-safe: every call re-inits exactly the cells it then contends on.
// ---------------------------------------------------------------------------
__global__ __launch_bounds__(256) void k_pw(
        const float* __restrict__ emb, const float* __restrict__ Wm,
        const float* __restrict__ bias, const int* __restrict__ loc,
        float* __restrict__ proj, int* __restrict__ winner) {
    int tid = threadIdx.x;
    int bx  = blockIdx.x;
    if (bx < NGEMM) {
        int c = tid & 31;
        int r = tid >> 5;                        // 0..7
        int row = bx * 8 + r;                    // flat entity index, 0..8191
        const f4* e4 = (const f4*)(emb + (size_t)row * DIN);
        const float* wc = Wm + c;
        float a0 = 0.f, a1 = 0.f, a2 = 0.f, a3 = 0.f;
        #pragma unroll 4
        for (int d4 = 0; d4 < DIN / 4; ++d4) {
            f4 ev = e4[d4];
            int d = d4 * 4;
            a0 += ev.x * wc[(size_t)(d + 0) * COUT];
            a1 += ev.y * wc[(size_t)(d + 1) * COUT];
            a2 += ev.z * wc[(size_t)(d + 2) * COUT];
            a3 += ev.w * wc[(size_t)(d + 3) * COUT];
        }
        proj[(size_t)row * COUT + c] = (a0 + a1) + (a2 + a3) + bias[c];
        return;
    }
    // winner block
    #pragma unroll
    for (int k = 0; k < BB * NN / 256; ++k) {
        int i = k * 256 + tid;
        int b = i >> 9;
        int h = loc[2 * i + 0];
        int w = loc[2 * i + 1];
        winner[b * HW + h * WWG + w] = -1;
    }
    __syncthreads();
    #pragma unroll
    for (int k = 0; k < BB * NN / 256; ++k) {
        int i = k * 256 + tid;
        int b = i >> 9;
        int h = loc[2 * i + 0];
        int w = loc[2 * i + 1];
        atomicMax(&winner[b * HW + h * WWG + w], i);
    }
}

// ---------------------------------------------------------------------------
// Node 2: out[b, ch, pix]: ch < 48 -> copy spatial; ch >= 48 -> zero.
// EXACT R2 pattern: 3D grid (64, 80, 16), one float4/thread, nontemporal.
// ---------------------------------------------------------------------------
__global__ __launch_bounds__(256) void k_fill(const float* __restrict__ sp,
                                              float* __restrict__ out) {
    int pix4 = blockIdx.x * 256 + threadIdx.x;   // f4 index within channel image
    int ch = blockIdx.y;
    int b  = blockIdx.z;
    f4 v = (f4)(0.0f);
    if (ch < CCS) {
        const f4* s = (const f4*)sp + (((size_t)(b * CCS + ch) << 14) + pix4);
        v = __builtin_nontemporal_load(s);
    }
    f4* o = (f4*)out + (((size_t)(b * CTOT + ch) << 14) + pix4);
    __builtin_nontemporal_store(v, o);
}

// ---------------------------------------------------------------------------
// Node 3: winning entity writes its 32-channel proj vector to out.
// ---------------------------------------------------------------------------
__global__ __launch_bounds__(256) void k_scatter(
        const float* __restrict__ proj, const int* __restrict__ loc,
        const int* __restrict__ winner, float* __restrict__ out) {
    int t = blockIdx.x * 256 + threadIdx.x;
    int c = t & 31;
    int i = t >> 5;                              // flat entity index
    int b = i >> 9;
    int h = loc[2 * i + 0];
    int w = loc[2 * i + 1];
    int cell = b * HW + h * WWG + w;
    if (winner[cell] != i) return;               // last-write-wins (max flat index)
    out[((size_t)(b * CTOT + CCS + c) << 16) + (size_t)h * WWG + w] =
        proj[(size_t)i * COUT + c];
}

extern "C" void kernel_launch(void* const* d_in, const int* in_sizes, int n_in,
                              void* d_out, int out_size, void* d_ws, size_t ws_size,
                              hipStream_t stream) {
    const float* sp   = (const float*)d_in[0];   // [16,48,256,256]
    const float* emb  = (const float*)d_in[1];   // [16,512,256]
    const float* Wm   = (const float*)d_in[2];   // [256,32]
    const float* bias = (const float*)d_in[3];   // [32]
    const int*   loc  = (const int*)d_in[4];     // [16,512,2]
    float* out = (float*)d_out;                  // [16,80,256,256]

    float* proj   = (float*)d_ws;                                     // 1 MB
    int*   winner = (int*)((char*)d_ws + (size_t)BB * NN * COUT * 4); // 4 MB

    hipLaunchKernelGGL(k_pw, dim3(NGEMM + 1), dim3(256), 0, stream,
                       emb, Wm, bias, loc, proj, winner);

    hipLaunchKernelGGL(k_fill, dim3(HW / 4 / 256, CTOT, BB), dim3(256), 0, stream,
                       sp, out);

    hipLaunchKernelGGL(k_scatter, dim3(BB * NN * COUT / 256), dim3(256), 0, stream,
                       proj, loc, winner, out);
}

// Round 8
// 127.598 us; speedup vs baseline: 1.1461x; 1.1461x over previous
//
#include <hip/hip_runtime.h>

typedef float f4 __attribute__((ext_vector_type(4)));

#define BB   16
#define NN   512
#define DIN  256
#define COUT 32
#define CCS  48
#define HH   256
#define WWG  256
#define HW   (HH * WWG)          // 65536 = 1<<16
#define CTOT (CCS + COUT)        // 80

// ---------------------------------------------------------------------------
// R2-proven: blocks [0,1024): proj = emb·W + b (8 entity-rows/block, W in LDS);
// blocks [1024,1056): winner atomicMax (one entity per thread, 32 parallel
// blocks). winner[] pre-set to -1 by async memset (0xFF).
// ---------------------------------------------------------------------------
__global__ __launch_bounds__(256) void k_projwin(
        const float* __restrict__ emb, const float* __restrict__ Wm,
        const float* __restrict__ bias, const int* __restrict__ loc,
        float* __restrict__ proj, int* __restrict__ winner) {
    __shared__ float Wl[DIN * COUT];
    int tid = threadIdx.x;
    if (blockIdx.x < 1024) {
        for (int i = tid; i < DIN * COUT; i += 256) Wl[i] = Wm[i];
        __syncthreads();
        int c = tid & 31;
        int r = tid >> 5;                        // 0..7
        int row = blockIdx.x * 8 + r;            // flat entity index, 0..8191
        const float* e = emb + (size_t)row * DIN;
        float acc = bias[c];
        #pragma unroll 8
        for (int d = 0; d < DIN; ++d)
            acc += e[d] * Wl[d * COUT + c];      // e[d] uniform broadcast; conflict-free
        proj[(size_t)row * COUT + c] = acc;
    } else {
        int i = (blockIdx.x - 1024) * 256 + tid; // flat entity index
        int b = i >> 9;
        int h = loc[2 * i + 0];
        int w = loc[2 * i + 1];
        atomicMax(&winner[b * HW + h * WWG + w], i);  // max flat == last-write-wins
    }
}

// ---------------------------------------------------------------------------
// Fill: out[b,ch,:] = spatial (ch<48) or zeros (ch>=48).
// ONE change vs R2: 4 f4 per thread, 16 KB contiguous per block (MLP=4).
// Grid (16, 80, 16). Loads issued back-to-back, then 4 NT stores; every
// wave-store is a contiguous 1 KB segment.
// ---------------------------------------------------------------------------
__global__ __launch_bounds__(256) void k_fill(const float* __restrict__ sp,
                                              float* __restrict__ out) {
    int tid   = threadIdx.x;
    int chunk = blockIdx.x;                      // 0..15 (1024-f4 chunks)
    int ch    = blockIdx.y;
    int b     = blockIdx.z;
    size_t base = ((size_t)(b * CTOT + ch) << 14) + chunk * 1024 + tid;
    f4* o = (f4*)out + base;
    if (ch < CCS) {
        const f4* s = (const f4*)sp + (((size_t)(b * CCS + ch) << 14) + chunk * 1024 + tid);
        f4 v0 = __builtin_nontemporal_load(s + 0 * 256);
        f4 v1 = __builtin_nontemporal_load(s + 1 * 256);
        f4 v2 = __builtin_nontemporal_load(s + 2 * 256);
        f4 v3 = __builtin_nontemporal_load(s + 3 * 256);
        __builtin_nontemporal_store(v0, o + 0 * 256);
        __builtin_nontemporal_store(v1, o + 1 * 256);
        __builtin_nontemporal_store(v2, o + 2 * 256);
        __builtin_nontemporal_store(v3, o + 3 * 256);
    } else {
        f4 z = (f4)(0.0f);
        __builtin_nontemporal_store(z, o + 0 * 256);
        __builtin_nontemporal_store(z, o + 1 * 256);
        __builtin_nontemporal_store(z, o + 2 * 256);
        __builtin_nontemporal_store(z, o + 3 * 256);
    }
}

// ---------------------------------------------------------------------------
// Winning entity writes its 32-channel proj vector to out[b, 48+c, h, w].
// ---------------------------------------------------------------------------
__global__ __launch_bounds__(256) void k_scatter(
        const float* __restrict__ proj, const int* __restrict__ loc,
        const int* __restrict__ winner, float* __restrict__ out) {
    int t = blockIdx.x * 256 + threadIdx.x;
    int c = t & 31;
    int i = t >> 5;                              // flat entity index
    int b = i >> 9;
    int h = loc[2 * i + 0];
    int w = loc[2 * i + 1];
    int cell = b * HW + h * WWG + w;
    if (winner[cell] != i) return;               // last-write-wins (max flat index)
    out[((size_t)(b * CTOT + CCS + c) << 16) + (size_t)h * WWG + w] =
        proj[(size_t)i * COUT + c];
}

extern "C" void kernel_launch(void* const* d_in, const int* in_sizes, int n_in,
                              void* d_out, int out_size, void* d_ws, size_t ws_size,
                              hipStream_t stream) {
    const float* sp   = (const float*)d_in[0];   // [16,48,256,256]
    const float* emb  = (const float*)d_in[1];   // [16,512,256]
    const float* Wm   = (const float*)d_in[2];   // [256,32]
    const float* bias = (const float*)d_in[3];   // [32]
    const int*   loc  = (const int*)d_in[4];     // [16,512,2]
    float* out = (float*)d_out;                  // [16,80,256,256]

    float* proj   = (float*)d_ws;                                     // 1 MB
    int*   winner = (int*)((char*)d_ws + (size_t)BB * NN * COUT * 4); // 4 MB

    hipMemsetAsync(winner, 0xFF, (size_t)BB * HW * sizeof(int), stream);

    hipLaunchKernelGGL(k_projwin, dim3(1024 + BB * NN / 256), dim3(256), 0, stream,
                       emb, Wm, bias, loc, proj, winner);

    hipLaunchKernelGGL(k_fill, dim3(HW / 4 / 1024, CTOT, BB), dim3(256), 0, stream,
                       sp, out);

    hipLaunchKernelGGL(k_scatter, dim3(BB * NN * COUT / 256), dim3(256), 0, stream,
                       proj, loc, winner, out);
}